// Round 2
// baseline (912.226 us; speedup 1.0000x reference)
//
#include <hip/hip_runtime.h>

// ---------------------------------------------------------------------------
// FractalAttention: B=4, L=4096, D=1024, H=16, DH=64, S=4
//
// Restructure: sq_s = x @ (ws[s]@wq).T + (ws[s]@bq + bs[s])   (same for k,v)
//  1. convert x, ws, wo to bf16; transpose wq/wk/wv to bf16
//  2. fuse weights:  Wf[s*3+t] = ws[s] @ w_t   (12x 1024^3 bf16 MFMA GEMM)
//  3. fuse biases:   bf[s*3+t] = ws[s] @ b_t + bs[s]          (fp32)
//  4. per row-chunk: proj (12 GEMMs batched) -> all-scale fused attention
//     (scale-combine in registers, bf16 out) -> final @ wo.T GEMM
// Workspace is sized at runtime against ws_size (round-1 abort was most
// likely a workspace overrun: 264MB used unchecked).
// ---------------------------------------------------------------------------

typedef unsigned short u16;
typedef __attribute__((ext_vector_type(8))) short s16x8;
typedef __attribute__((ext_vector_type(8))) unsigned short u16x8;
typedef __attribute__((ext_vector_type(4))) float f32x4;

#define MM 16384        // B*L
#define DDIM 1024
#define DDSQ 1048576ull // D*D

__device__ __forceinline__ u16 f2bf(float f) {
  unsigned u = __float_as_uint(f);
  u = (u + 0x7FFFu + ((u >> 16) & 1u)) >> 16;   // RNE
  return (u16)u;
}
__device__ __forceinline__ float b2f(u16 b) {
  return __uint_as_float(((unsigned)b) << 16);
}
__device__ __forceinline__ void gload_lds16(const void* g, void* l) {
  __builtin_amdgcn_global_load_lds(
      (const __attribute__((address_space(1))) void*)g,
      (__attribute__((address_space(3))) void*)l, 16, 0, 0);
}

// ---------------------------------------------------------------------------
// f32 -> bf16 convert (vectorized x4)
// ---------------------------------------------------------------------------
__global__ __launch_bounds__(256) void k_f32_to_bf16(
    const float* __restrict__ in, u16* __restrict__ out, int n4) {
  int i = blockIdx.x * 256 + threadIdx.x;
  if (i >= n4) return;
  float4 v = reinterpret_cast<const float4*>(in)[i];
  ushort4 o;
  o.x = f2bf(v.x); o.y = f2bf(v.y); o.z = f2bf(v.z); o.w = f2bf(v.w);
  reinterpret_cast<ushort4*>(out)[i] = o;
}

// ---------------------------------------------------------------------------
// transpose wq/wk/wv (1024x1024 f32) -> bf16, out[t][d][m] = w_t[m][d]
// ---------------------------------------------------------------------------
__global__ __launch_bounds__(256) void k_transpose_bf16(
    const float* __restrict__ wq, const float* __restrict__ wk,
    const float* __restrict__ wv, u16* __restrict__ out) {
  __shared__ float tile[32][33];
  const float* src = (blockIdx.z == 0) ? wq : (blockIdx.z == 1) ? wk : wv;
  u16* dst = out + (size_t)blockIdx.z * DDSQ;
  int tx = threadIdx.x, ty = threadIdx.y;
  int bx = blockIdx.x * 32, by = blockIdx.y * 32;
#pragma unroll
  for (int i = 0; i < 4; ++i)
    tile[ty + 8 * i][tx] = src[(size_t)(by + ty + 8 * i) * DDIM + bx + tx];
  __syncthreads();
#pragma unroll
  for (int i = 0; i < 4; ++i)
    dst[(size_t)(bx + ty + 8 * i) * DDIM + by + tx] = f2bf(tile[tx][ty + 8 * i]);
}

// ---------------------------------------------------------------------------
// fused bias: bf[idx = s*3+t][e] = dot(ws[s][e][:], b_t) + bs[s][e]   (fp32)
// ---------------------------------------------------------------------------
__global__ __launch_bounds__(256) void k_bias_fuse(
    const float* __restrict__ ws, const float* __restrict__ bq,
    const float* __restrict__ bk, const float* __restrict__ bv,
    const float* __restrict__ bs, float* __restrict__ bf) {
  int idx = blockIdx.y;
  int s = idx / 3, t = idx - s * 3;
  const float* bt = (t == 0) ? bq : (t == 1) ? bk : bv;
  int lane = threadIdx.x & 63, wid = threadIdx.x >> 6;
  int e = blockIdx.x * 4 + wid;
  const float* wr = ws + (size_t)s * DDSQ + (size_t)e * DDIM;
  float p = 0.f;
  for (int j = lane; j < DDIM; j += 64) p += wr[j] * bt[j];
#pragma unroll
  for (int off = 32; off > 0; off >>= 1) p += __shfl_xor(p, off);
  if (lane == 0) bf[idx * DDIM + e] = p + bs[s * DDIM + e];
}

// ---------------------------------------------------------------------------
// bf16 GEMM, C = A @ B^T (+bias):  A MxK row-major, B NxK row-major.
// 128x128 tile, BK=32, 256 threads (2x2 waves of 64x64), 16x16x32 bf16 MFMA,
// global_load_lds width-16 staging (m97 structure).
// ---------------------------------------------------------------------------
template <typename OutT>
__global__ __launch_bounds__(256) void k_gemm_bt(
    const u16* __restrict__ A, const u16* __restrict__ B, OutT* __restrict__ C,
    const float* __restrict__ bias, int M, int N, int K,
    size_t za, size_t zb, size_t zc, size_t zbias, int zmode) {
  __shared__ u16 lds_a[128 * 32];
  __shared__ u16 lds_b[128 * 32];

  int z = blockIdx.z;
  if (zmode == 1) { A += (size_t)(z / 3) * za; B += (size_t)(z % 3) * zb; }
  else            { A += (size_t)z * za;       B += (size_t)z * zb; }
  C += (size_t)z * zc;
  const float* biasz = bias ? (bias + (size_t)z * zbias) : nullptr;

  int m0 = blockIdx.x * 128, n0 = blockIdx.y * 128;
  int tid = threadIdx.x;
  int lane = tid & 63, wid = tid >> 6;
  int wm = wid >> 1, wn = wid & 1;   // 2x2 wave grid, 64x64 each

  f32x4 acc[4][4] = {};

  // staging: 8 chunks of 1024B per matrix; wave w issues chunks {2w, 2w+1}
  auto stage = [&](int k0) {
#pragma unroll
    for (int i = 0; i < 2; ++i) {
      int c = wid * 2 + i;
      int row = c * 16 + (lane >> 2);
      int col = (lane & 3) * 8;
      gload_lds16(A + (size_t)(m0 + row) * K + k0 + col, &lds_a[c * 512]);
      gload_lds16(B + (size_t)(n0 + row) * K + k0 + col, &lds_b[c * 512]);
    }
  };

  stage(0);
  int ar = (wm * 64 + (lane & 15)) * 32 + (lane >> 4) * 8;
  int br = (wn * 64 + (lane & 15)) * 32 + (lane >> 4) * 8;
  for (int k0 = 0;;) {
    __syncthreads();
    s16x8 af[4], bfr[4];
#pragma unroll
    for (int mi = 0; mi < 4; ++mi)
      af[mi] = *reinterpret_cast<const s16x8*>(&lds_a[ar + mi * 16 * 32]);
#pragma unroll
    for (int ni = 0; ni < 4; ++ni)
      bfr[ni] = *reinterpret_cast<const s16x8*>(&lds_b[br + ni * 16 * 32]);
#pragma unroll
    for (int mi = 0; mi < 4; ++mi)
#pragma unroll
      for (int ni = 0; ni < 4; ++ni)
        acc[mi][ni] = __builtin_amdgcn_mfma_f32_16x16x32_bf16(
            af[mi], bfr[ni], acc[mi][ni], 0, 0, 0);
    k0 += 32;
    if (k0 >= K) break;
    __syncthreads();
    stage(k0);
  }

  // epilogue: C row = (lane>>4)*4 + r, col = lane&15 within each 16x16
#pragma unroll
  for (int mi = 0; mi < 4; ++mi) {
#pragma unroll
    for (int ni = 0; ni < 4; ++ni) {
      int colg = n0 + wn * 64 + ni * 16 + (lane & 15);
      float badd = biasz ? biasz[colg] : 0.f;
#pragma unroll
      for (int r = 0; r < 4; ++r) {
        int rowg = m0 + wm * 64 + mi * 16 + ((lane >> 4) << 2) + r;
        float v = acc[mi][ni][r] + badd;
        if constexpr (sizeof(OutT) == 2) C[(size_t)rowg * N + colg] = f2bf(v);
        else                             C[(size_t)rowg * N + colg] = v;
      }
    }
  }
}

// ---------------------------------------------------------------------------
// per-position head-mix attention, ALL 4 scales fused, chunk-local.
// 1 wave per block, 4 positions; lane = (p<<4) | h.
// proj holds 12 matrices [s*3+t][rows][1024] (bf16).
// acc[d] = sum_s w_s * softmax_g(q_s.k_s/8) @ v_s   (registers, fp32)
// ---------------------------------------------------------------------------
__global__ __launch_bounds__(64) void k_attn_all(
    const u16* __restrict__ proj, u16* __restrict__ outbf,
    const float* __restrict__ sl, int rows) {
  __shared__ u16 kl[4096];
  __shared__ u16 vl[4096];
  int lane = threadIdx.x;
  int m0 = blockIdx.x * 4;
  int p = lane >> 4, h = lane & 15;

  // scale weights: softmax(scale_logits)
  float l0 = sl[0], l1 = sl[1], l2 = sl[2], l3 = sl[3];
  float lm = fmaxf(fmaxf(l0, l1), fmaxf(l2, l3));
  float e0 = __expf(l0 - lm), e1 = __expf(l1 - lm), e2 = __expf(l2 - lm),
        e3 = __expf(l3 - lm);
  float esum = e0 + e1 + e2 + e3;
  float wsc4[4] = {e0 / esum, e1 / esum, e2 / esum, e3 / esum};

  float acc[64];
#pragma unroll
  for (int i = 0; i < 64; ++i) acc[i] = 0.f;

  for (int s = 0; s < 4; ++s) {
    const u16* q = proj + (size_t)(3 * s + 0) * rows * DDIM;
    const u16* k = proj + (size_t)(3 * s + 1) * rows * DDIM;
    const u16* v = proj + (size_t)(3 * s + 2) * rows * DDIM;

    if (s) {  // make sure prior LDS reads are done before DMA overwrites
      asm volatile("s_waitcnt vmcnt(0) lgkmcnt(0)" ::: "memory");
      __syncthreads();
    }
    // stage K, V for 4 positions (16 KB), coalesced direct-to-LDS
#pragma unroll
    for (int j = 0; j < 8; ++j) {
      int pp = j >> 1;
      int e = ((j & 1) << 9) + lane * 8;
      gload_lds16(k + (size_t)(m0 + pp) * DDIM + e, &kl[j * 512]);
      gload_lds16(v + (size_t)(m0 + pp) * DDIM + e, &vl[j * 512]);
    }

    // q row for this lane, direct from global
    const u16* qrow = q + (size_t)(m0 + p) * DDIM + h * 64;
    float qf[64];
#pragma unroll
    for (int j = 0; j < 8; ++j) {
      u16x8 qv = *reinterpret_cast<const u16x8*>(qrow + j * 8);
#pragma unroll
      for (int i = 0; i < 8; ++i) qf[j * 8 + i] = b2f(qv[i]);
    }
    asm volatile("s_waitcnt vmcnt(0)" ::: "memory");  // DMA-to-LDS complete
    __syncthreads();

    // scores
    float sc[16];
#pragma unroll
    for (int g = 0; g < 16; ++g) {
      float dot = 0.f;
      const u16* kr = kl + p * 1024 + g * 64;
#pragma unroll
      for (int j = 0; j < 8; ++j) {
        u16x8 kv = *reinterpret_cast<const u16x8*>(kr + j * 8);
#pragma unroll
        for (int i = 0; i < 8; ++i) dot = fmaf(b2f(kv[i]), qf[j * 8 + i], dot);
      }
      sc[g] = dot * 0.125f;
    }

    // lane-local softmax over g
    float mx = sc[0];
#pragma unroll
    for (int g = 1; g < 16; ++g) mx = fmaxf(mx, sc[g]);
    float sum = 0.f;
#pragma unroll
    for (int g = 0; g < 16; ++g) { sc[g] = __expf(sc[g] - mx); sum += sc[g]; }
    float inv = wsc4[s] / sum;
#pragma unroll
    for (int g = 0; g < 16; ++g) sc[g] *= inv;

    // PV: acc[d] += w_s * attn[g] * v[g,d]
#pragma unroll
    for (int g = 0; g < 16; ++g) {
      float a = sc[g];
      const u16* vr = vl + p * 1024 + g * 64;
#pragma unroll
      for (int j = 0; j < 8; ++j) {
        u16x8 vv = *reinterpret_cast<const u16x8*>(vr + j * 8);
#pragma unroll
        for (int i = 0; i < 8; ++i)
          acc[j * 8 + i] = fmaf(a, b2f(vv[i]), acc[j * 8 + i]);
      }
    }
  }

  // write combined result as bf16
  size_t base = (size_t)(m0 + p) * DDIM + h * 64;
#pragma unroll
  for (int j = 0; j < 16; ++j) {
    ushort4 o;
    o.x = f2bf(acc[4 * j]);
    o.y = f2bf(acc[4 * j + 1]);
    o.z = f2bf(acc[4 * j + 2]);
    o.w = f2bf(acc[4 * j + 3]);
    reinterpret_cast<ushort4*>(outbf + base)[j] = o;
  }
}

// ---------------------------------------------------------------------------
extern "C" void kernel_launch(void* const* d_in, const int* in_sizes, int n_in,
                              void* d_out, int out_size, void* d_ws,
                              size_t ws_size, hipStream_t stream) {
  const float* x  = (const float*)d_in[0];
  const float* sl = (const float*)d_in[1];
  const float* wq = (const float*)d_in[2];
  const float* bq = (const float*)d_in[3];
  const float* wk = (const float*)d_in[4];
  const float* bk = (const float*)d_in[5];
  const float* wv = (const float*)d_in[6];
  const float* bv = (const float*)d_in[7];
  const float* wo = (const float*)d_in[8];
  const float* bo = (const float*)d_in[9];
  const float* ws = (const float*)d_in[10];
  const float* bs = (const float*)d_in[11];
  float* out = (float*)d_out;

  char* wsb = (char*)d_ws;
  size_t off = 0;
  u16* xbf    = (u16*)(wsb + off); off += (size_t)MM * DDIM * 2;   // 32 MB
  u16* wfus   = (u16*)(wsb + off); off += 12ull * DDSQ * 2;        // 24 MB
  u16* wobf   = (u16*)(wsb + off); off += DDSQ * 2;                // 2 MB
  float* bfus = (float*)(wsb + off); off += 65536;                 // 48 KB pad
  char* dynr  = wsb + off;
  size_t fixed = off;

  // dynamic region: 12 proj chunks + 1 combine chunk (bf16, chunk x 1024 each)
  int chunk = 4096;
  while (chunk > 128 && fixed + (size_t)13 * chunk * DDIM * 2 > ws_size)
    chunk >>= 1;
  u16* projc = (u16*)dynr;
  u16* combc = (u16*)(dynr + (size_t)12 * chunk * DDIM * 2);
  // prefuse-phase overlay (dead before any projc/combc write):
  u16* wtT  = (u16*)dynr;                    // 6 MB
  u16* wsbf = (u16*)(dynr + 3ull * DDSQ * 2); // 8 MB

  int n4;
  n4 = MM * DDIM / 4;
  k_f32_to_bf16<<<(n4 + 255) / 256, 256, 0, stream>>>(x, xbf, n4);
  n4 = (int)(4 * DDSQ / 4);
  k_f32_to_bf16<<<(n4 + 255) / 256, 256, 0, stream>>>(ws, wsbf, n4);
  n4 = (int)(DDSQ / 4);
  k_f32_to_bf16<<<(n4 + 255) / 256, 256, 0, stream>>>(wo, wobf, n4);

  k_transpose_bf16<<<dim3(32, 32, 3), dim3(32, 8), 0, stream>>>(wq, wk, wv, wtT);
  k_bias_fuse<<<dim3(256, 12), 256, 0, stream>>>(ws, bq, bk, bv, bs, bfus);

  // fused weights: Wf[s*3+t] = ws_bf[s] @ wtT[t]^T   (1024^3 each, z=12)
  k_gemm_bt<u16><<<dim3(8, 8, 12), 256, 0, stream>>>(
      wsbf, wtT, wfus, nullptr, 1024, 1024, 1024, DDSQ, DDSQ, DDSQ, 0, 1);

  // chunked: proj (12 batched) -> fused attention -> final @ wo.T
  int nchunks = MM / chunk;
  for (int c = 0; c < nchunks; ++c) {
    const u16* xa = xbf + (size_t)c * chunk * DDIM;
    k_gemm_bt<u16><<<dim3(chunk / 128, 8, 12), 256, 0, stream>>>(
        xa, wfus, projc, bfus, chunk, 1024, 1024,
        0, DDSQ, (size_t)chunk * DDIM, DDIM, 0);
    k_attn_all<<<dim3(chunk / 4), 64, 0, stream>>>(projc, combc, sl, chunk);
    k_gemm_bt<float><<<dim3(chunk / 128, 8, 1), 256, 0, stream>>>(
        combc, wobf, out + (size_t)c * chunk * DDIM, bo, chunk, 1024, 1024,
        0, 0, 0, 0, 0);
  }
}

// Round 3
// 827.870 us; speedup vs baseline: 1.1019x; 1.1019x over previous
//
#include <hip/hip_runtime.h>

// ---------------------------------------------------------------------------
// FractalAttention: B=4, L=4096, D=1024, H=16, DH=64, S=4
//
// Restructure: sq_s = x @ (ws[s]@wq).T + (ws[s]@bq + bs[s])   (same for k,v)
//  1. convert x, ws, wo to bf16; transpose wq/wk/wv to bf16
//  2. fuse weights:  Wf[s*3+t] = ws[s] @ w_t   (12x 1024^3 bf16 MFMA GEMM)
//  3. fuse biases:   bf[s*3+t] = ws[s] @ b_t + bs[s]          (fp32)
//  4. per row-chunk: proj (12 GEMMs batched) -> all-scale fused attention
//     (wave = 1 position, lane = (head, d-quarter), scale-combine in regs)
//  5. single final GEMM over all rows: out = comb @ wo.T + bo
// ---------------------------------------------------------------------------

typedef unsigned short u16;
typedef __attribute__((ext_vector_type(8))) short s16x8;
typedef __attribute__((ext_vector_type(8))) unsigned short u16x8;
typedef __attribute__((ext_vector_type(4))) float f32x4;

#define MM 16384        // B*L
#define DDIM 1024
#define DDSQ 1048576ull // D*D

__device__ __forceinline__ u16 f2bf(float f) {
  unsigned u = __float_as_uint(f);
  u = (u + 0x7FFFu + ((u >> 16) & 1u)) >> 16;   // RNE
  return (u16)u;
}
__device__ __forceinline__ float b2f(u16 b) {
  return __uint_as_float(((unsigned)b) << 16);
}
__device__ __forceinline__ void gload_lds16(const void* g, void* l) {
  __builtin_amdgcn_global_load_lds(
      (const __attribute__((address_space(1))) void*)g,
      (__attribute__((address_space(3))) void*)l, 16, 0, 0);
}

// ---------------------------------------------------------------------------
// f32 -> bf16 convert (vectorized x4)
// ---------------------------------------------------------------------------
__global__ __launch_bounds__(256) void k_f32_to_bf16(
    const float* __restrict__ in, u16* __restrict__ out, int n4) {
  int i = blockIdx.x * 256 + threadIdx.x;
  if (i >= n4) return;
  float4 v = reinterpret_cast<const float4*>(in)[i];
  ushort4 o;
  o.x = f2bf(v.x); o.y = f2bf(v.y); o.z = f2bf(v.z); o.w = f2bf(v.w);
  reinterpret_cast<ushort4*>(out)[i] = o;
}

// ---------------------------------------------------------------------------
// transpose wq/wk/wv (1024x1024 f32) -> bf16, out[t][d][m] = w_t[m][d]
// ---------------------------------------------------------------------------
__global__ __launch_bounds__(256) void k_transpose_bf16(
    const float* __restrict__ wq, const float* __restrict__ wk,
    const float* __restrict__ wv, u16* __restrict__ out) {
  __shared__ float tile[32][33];
  const float* src = (blockIdx.z == 0) ? wq : (blockIdx.z == 1) ? wk : wv;
  u16* dst = out + (size_t)blockIdx.z * DDSQ;
  int tx = threadIdx.x, ty = threadIdx.y;
  int bx = blockIdx.x * 32, by = blockIdx.y * 32;
#pragma unroll
  for (int i = 0; i < 4; ++i)
    tile[ty + 8 * i][tx] = src[(size_t)(by + ty + 8 * i) * DDIM + bx + tx];
  __syncthreads();
#pragma unroll
  for (int i = 0; i < 4; ++i)
    dst[(size_t)(bx + ty + 8 * i) * DDIM + by + tx] = f2bf(tile[tx][ty + 8 * i]);
}

// ---------------------------------------------------------------------------
// fused bias: bf[idx = s*3+t][e] = dot(ws[s][e][:], b_t) + bs[s][e]   (fp32)
// ---------------------------------------------------------------------------
__global__ __launch_bounds__(256) void k_bias_fuse(
    const float* __restrict__ ws, const float* __restrict__ bq,
    const float* __restrict__ bk, const float* __restrict__ bv,
    const float* __restrict__ bs, float* __restrict__ bf) {
  int idx = blockIdx.y;
  int s = idx / 3, t = idx - s * 3;
  const float* bt = (t == 0) ? bq : (t == 1) ? bk : bv;
  int lane = threadIdx.x & 63, wid = threadIdx.x >> 6;
  int e = blockIdx.x * 4 + wid;
  const float* wr = ws + (size_t)s * DDSQ + (size_t)e * DDIM;
  float p = 0.f;
  for (int j = lane; j < DDIM; j += 64) p += wr[j] * bt[j];
#pragma unroll
  for (int off = 32; off > 0; off >>= 1) p += __shfl_xor(p, off);
  if (lane == 0) bf[idx * DDIM + e] = p + bs[s * DDIM + e];
}

// ---------------------------------------------------------------------------
// bf16 GEMM, C = A @ B^T (+bias):  A MxK row-major, B NxK row-major.
// 128x128 tile, BK=32, 256 threads (2x2 waves of 64x64), 16x16x32 bf16 MFMA,
// global_load_lds width-16 staging (m97 structure).
// Grid: (8*Z, M/128); blockIdx.x = z*8 + n_blk so that 8*Z consecutive
// blocks share one A-panel (L2-hot A, L3-resident B).
// ---------------------------------------------------------------------------
template <typename OutT>
__global__ __launch_bounds__(256) void k_gemm_bt(
    const u16* __restrict__ A, const u16* __restrict__ B, OutT* __restrict__ C,
    const float* __restrict__ bias, int M, int N, int K,
    size_t za, size_t zb, size_t zc, size_t zbias, int zmode) {
  __shared__ u16 lds_a[128 * 32];
  __shared__ u16 lds_b[128 * 32];

  int z = blockIdx.x >> 3;
  int n_blk = blockIdx.x & 7;
  int m_blk = blockIdx.y;
  if (zmode == 1) { A += (size_t)(z / 3) * za; B += (size_t)(z % 3) * zb; }
  else            { A += (size_t)z * za;       B += (size_t)z * zb; }
  C += (size_t)z * zc;
  const float* biasz = bias ? (bias + (size_t)z * zbias) : nullptr;

  int m0 = m_blk * 128, n0 = n_blk * 128;
  int tid = threadIdx.x;
  int lane = tid & 63, wid = tid >> 6;
  int wm = wid >> 1, wn = wid & 1;   // 2x2 wave grid, 64x64 each

  f32x4 acc[4][4] = {};

  // staging: 8 chunks of 1024B per matrix; wave w issues chunks {2w, 2w+1}
  auto stage = [&](int k0) {
#pragma unroll
    for (int i = 0; i < 2; ++i) {
      int c = wid * 2 + i;
      int row = c * 16 + (lane >> 2);
      int col = (lane & 3) * 8;
      gload_lds16(A + (size_t)(m0 + row) * K + k0 + col, &lds_a[c * 512]);
      gload_lds16(B + (size_t)(n0 + row) * K + k0 + col, &lds_b[c * 512]);
    }
  };

  stage(0);
  int ar = (wm * 64 + (lane & 15)) * 32 + (lane >> 4) * 8;
  int br = (wn * 64 + (lane & 15)) * 32 + (lane >> 4) * 8;
  for (int k0 = 0;;) {
    __syncthreads();
    s16x8 af[4], bfr[4];
#pragma unroll
    for (int mi = 0; mi < 4; ++mi)
      af[mi] = *reinterpret_cast<const s16x8*>(&lds_a[ar + mi * 16 * 32]);
#pragma unroll
    for (int ni = 0; ni < 4; ++ni)
      bfr[ni] = *reinterpret_cast<const s16x8*>(&lds_b[br + ni * 16 * 32]);
#pragma unroll
    for (int mi = 0; mi < 4; ++mi)
#pragma unroll
      for (int ni = 0; ni < 4; ++ni)
        acc[mi][ni] = __builtin_amdgcn_mfma_f32_16x16x32_bf16(
            af[mi], bfr[ni], acc[mi][ni], 0, 0, 0);
    k0 += 32;
    if (k0 >= K) break;
    __syncthreads();
    stage(k0);
  }

  // epilogue: C row = (lane>>4)*4 + r, col = lane&15 within each 16x16
#pragma unroll
  for (int mi = 0; mi < 4; ++mi) {
#pragma unroll
    for (int ni = 0; ni < 4; ++ni) {
      int colg = n0 + wn * 64 + ni * 16 + (lane & 15);
      float badd = biasz ? biasz[colg] : 0.f;
#pragma unroll
      for (int r = 0; r < 4; ++r) {
        int rowg = m0 + wm * 64 + mi * 16 + ((lane >> 4) << 2) + r;
        float v = acc[mi][ni][r] + badd;
        if constexpr (sizeof(OutT) == 2) C[(size_t)rowg * N + colg] = f2bf(v);
        else                             C[(size_t)rowg * N + colg] = v;
      }
    }
  }
}

// ---------------------------------------------------------------------------
// per-position head-mix attention, ALL 4 scales fused.
// 256 threads = 4 waves; wave = 1 position (row = blockIdx.x*4 + wid).
// lane = h*4 + dq: head h (0..15), d-quarter dq (0..3) -> 16 d-elems/lane.
// Per scale: stage K,V row (4KB) into this wave's private LDS region via
// global_load_lds; score partial-dot + 4-lane shfl_xor reduce; lane-local
// softmax; PV accumulate (w_s-scaled) into acc[16].
// No cross-wave sharing -> no __syncthreads at all.
// ---------------------------------------------------------------------------
__global__ __launch_bounds__(256) void k_attn_all(
    const u16* __restrict__ proj, u16* __restrict__ outbf,
    const float* __restrict__ sl, int rows) {
  __shared__ u16 kv[4][2][1024];   // [wave][K/V][1024]
  int lane = threadIdx.x & 63, wid = threadIdx.x >> 6;
  int row = blockIdx.x * 4 + wid;
  int h = lane >> 2, dq = lane & 3;
  int doff = h * 64 + dq * 16;

  // scale weights: softmax(scale_logits)
  float l0 = sl[0], l1 = sl[1], l2 = sl[2], l3 = sl[3];
  float lm = fmaxf(fmaxf(l0, l1), fmaxf(l2, l3));
  float e0 = __expf(l0 - lm), e1 = __expf(l1 - lm), e2 = __expf(l2 - lm),
        e3 = __expf(l3 - lm);
  float esum = e0 + e1 + e2 + e3;
  float wsc4[4] = {e0 / esum, e1 / esum, e2 / esum, e3 / esum};

  float acc[16];
#pragma unroll
  for (int i = 0; i < 16; ++i) acc[i] = 0.f;

  for (int s = 0; s < 4; ++s) {
    const u16* kr = proj + ((size_t)(3 * s + 1) * rows + row) * DDIM;
    const u16* vr = proj + ((size_t)(3 * s + 2) * rows + row) * DDIM;
    // drain prior-scale LDS reads and DMA before overwriting our region
    asm volatile("s_waitcnt vmcnt(0) lgkmcnt(0)" ::: "memory");
    gload_lds16(kr + lane * 8,       &kv[wid][0][0]);
    gload_lds16(kr + 512 + lane * 8, &kv[wid][0][512]);
    gload_lds16(vr + lane * 8,       &kv[wid][1][0]);
    gload_lds16(vr + 512 + lane * 8, &kv[wid][1][512]);

    // q slice for this lane (score scale 1/8 folded in)
    const u16* qr = proj + ((size_t)(3 * s) * rows + row) * DDIM + doff;
    u16x8 q0 = *reinterpret_cast<const u16x8*>(qr);
    u16x8 q1 = *reinterpret_cast<const u16x8*>(qr + 8);
    float qf[16];
#pragma unroll
    for (int i = 0; i < 8; ++i) {
      qf[i]     = b2f(q0[i]) * 0.125f;
      qf[8 + i] = b2f(q1[i]) * 0.125f;
    }
    asm volatile("s_waitcnt vmcnt(0)" ::: "memory");  // DMA-to-LDS complete

    // scores: partial dot over this lane's 16 d-elems, reduce over dq group
    float sc[16];
#pragma unroll
    for (int g = 0; g < 16; ++g) {
      const u16* kp = &kv[wid][0][g * 64 + dq * 16];
      u16x8 k0 = *reinterpret_cast<const u16x8*>(kp);
      u16x8 k1 = *reinterpret_cast<const u16x8*>(kp + 8);
      float d = 0.f;
#pragma unroll
      for (int i = 0; i < 8; ++i) d = fmaf(qf[i], b2f(k0[i]), d);
#pragma unroll
      for (int i = 0; i < 8; ++i) d = fmaf(qf[8 + i], b2f(k1[i]), d);
      d += __shfl_xor(d, 1);
      d += __shfl_xor(d, 2);
      sc[g] = d;
    }

    // lane-local softmax over g (replicated across the 4-lane group)
    float mx = sc[0];
#pragma unroll
    for (int g = 1; g < 16; ++g) mx = fmaxf(mx, sc[g]);
    float sum = 0.f;
#pragma unroll
    for (int g = 0; g < 16; ++g) { sc[g] = __expf(sc[g] - mx); sum += sc[g]; }
    float inv = wsc4[s] / sum;
#pragma unroll
    for (int g = 0; g < 16; ++g) sc[g] *= inv;

    // PV: acc[i] += w_s * attn[g] * v[g, doff+i]
#pragma unroll
    for (int g = 0; g < 16; ++g) {
      float a = sc[g];
      const u16* vp = &kv[wid][1][g * 64 + dq * 16];
      u16x8 v0 = *reinterpret_cast<const u16x8*>(vp);
      u16x8 v1 = *reinterpret_cast<const u16x8*>(vp + 8);
#pragma unroll
      for (int i = 0; i < 8; ++i) {
        acc[i]     = fmaf(a, b2f(v0[i]), acc[i]);
        acc[8 + i] = fmaf(a, b2f(v1[i]), acc[8 + i]);
      }
    }
  }

  // write combined result as bf16 (wave writes one contiguous 2KB row)
  u16* op = outbf + (size_t)row * DDIM + doff;
  u16x8 o0, o1;
#pragma unroll
  for (int i = 0; i < 8; ++i) {
    o0[i] = f2bf(acc[i]);
    o1[i] = f2bf(acc[8 + i]);
  }
  *reinterpret_cast<u16x8*>(op) = o0;
  *reinterpret_cast<u16x8*>(op + 8) = o1;
}

// ---------------------------------------------------------------------------
extern "C" void kernel_launch(void* const* d_in, const int* in_sizes, int n_in,
                              void* d_out, int out_size, void* d_ws,
                              size_t ws_size, hipStream_t stream) {
  const float* x  = (const float*)d_in[0];
  const float* sl = (const float*)d_in[1];
  const float* wq = (const float*)d_in[2];
  const float* bq = (const float*)d_in[3];
  const float* wk = (const float*)d_in[4];
  const float* bk = (const float*)d_in[5];
  const float* wv = (const float*)d_in[6];
  const float* bv = (const float*)d_in[7];
  const float* wo = (const float*)d_in[8];
  const float* bo = (const float*)d_in[9];
  const float* ws = (const float*)d_in[10];
  const float* bs = (const float*)d_in[11];
  float* out = (float*)d_out;

  char* wsb = (char*)d_ws;
  size_t off = 0;
  u16* xbf    = (u16*)(wsb + off); off += (size_t)MM * DDIM * 2;   // 32 MB
  u16* wfus   = (u16*)(wsb + off); off += 12ull * DDSQ * 2;        // 24 MB
  u16* wobf   = (u16*)(wsb + off); off += DDSQ * 2;                // 2 MB
  float* bfus = (float*)(wsb + off); off += 65536;                 // 48 KB + pad
  u16* combc  = (u16*)(wsb + off); off += (size_t)MM * DDIM * 2;   // 32 MB
  char* dynr  = wsb + off;
  size_t fixed = off;

  // dynamic region: 12 proj chunk matrices (bf16, chunk x 1024 each)
  int chunk = 4096;
  while (chunk > 1024 && fixed + (size_t)12 * chunk * DDIM * 2 > ws_size)
    chunk >>= 1;
  u16* projc = (u16*)dynr;
  // prefuse-phase overlay (dead before any projc write); needs 14 MB,
  // dyn region is >= 24 MB at chunk >= 1024.
  u16* wtT  = (u16*)dynr;                      // 6 MB
  u16* wsbf = (u16*)(dynr + 3ull * DDSQ * 2);  // 8 MB

  int n4;
  n4 = MM * DDIM / 4;
  k_f32_to_bf16<<<(n4 + 255) / 256, 256, 0, stream>>>(x, xbf, n4);
  n4 = (int)(4 * DDSQ / 4);
  k_f32_to_bf16<<<(n4 + 255) / 256, 256, 0, stream>>>(ws, wsbf, n4);
  n4 = (int)(DDSQ / 4);
  k_f32_to_bf16<<<(n4 + 255) / 256, 256, 0, stream>>>(wo, wobf, n4);

  k_transpose_bf16<<<dim3(32, 32, 3), dim3(32, 8), 0, stream>>>(wq, wk, wv, wtT);
  k_bias_fuse<<<dim3(256, 12), 256, 0, stream>>>(ws, bq, bk, bv, bs, bfus);

  // fused weights: Wf[s*3+t] = ws_bf[s] @ wtT[t]^T   (1024^3 each, z=12)
  k_gemm_bt<u16><<<dim3(96, 8), 256, 0, stream>>>(
      wsbf, wtT, wfus, nullptr, 1024, 1024, 1024, DDSQ, DDSQ, DDSQ, 0, 1);

  // chunked: proj (12 batched) -> fused attention (writes combc slice)
  int nchunks = MM / chunk;
  for (int c = 0; c < nchunks; ++c) {
    const u16* xa = xbf + (size_t)c * chunk * DDIM;
    k_gemm_bt<u16><<<dim3(96, chunk / 128), 256, 0, stream>>>(
        xa, wfus, projc, bfus, chunk, 1024, 1024,
        0, DDSQ, (size_t)chunk * DDIM, DDIM, 0);
    k_attn_all<<<dim3(chunk / 4), 256, 0, stream>>>(
        projc, combc + (size_t)c * chunk * DDIM, sl, chunk);
  }

  // single final GEMM: out = comb_bf @ wo^T + bo   (fp32 output)
  k_gemm_bt<float><<<dim3(8, 128), 256, 0, stream>>>(
      combc, wobf, out, bo, MM, 1024, 1024, 0, 0, 0, 0, 0);
}

// Round 4
// 754.400 us; speedup vs baseline: 1.2092x; 1.0974x over previous
//
#include <hip/hip_runtime.h>

// ---------------------------------------------------------------------------
// FractalAttention: B=4, L=4096, D=1024, H=16, DH=64, S=4
//
//  sq_s = x @ (ws[s]@wq).T + (ws[s]@bq + bs[s])   (same for k,v)
//  1. convert x, ws, wo to bf16; transpose wq/wk/wv to bf16
//  2. fuse weights:  Wf[s*3+t] = ws[s] @ w_t   (12x 1024^3, m97 GEMM)
//  3. fuse biases:   bf[s*3+t] = ws[s] @ b_t + bs[s]
//  4. per row-chunk: proj (12 batched) via 256x256 counted-vmcnt pipelined
//     GEMM (T3+T4+T5+swizzle) -> all-scale fused attention
//  5. single final GEMM: out = comb @ wo.T + bo   (m97 GEMM, f32 out)
// ---------------------------------------------------------------------------

typedef unsigned short u16;
typedef __attribute__((ext_vector_type(8))) short s16x8;
typedef __attribute__((ext_vector_type(8))) unsigned short u16x8;
typedef __attribute__((ext_vector_type(4))) float f32x4;

#define MM 16384        // B*L
#define DDIM 1024
#define DDSQ 1048576ull // D*D

__device__ __forceinline__ u16 f2bf(float f) {
  unsigned u = __float_as_uint(f);
  u = (u + 0x7FFFu + ((u >> 16) & 1u)) >> 16;   // RNE
  return (u16)u;
}
__device__ __forceinline__ float b2f(u16 b) {
  return __uint_as_float(((unsigned)b) << 16);
}
__device__ __forceinline__ void gload_lds16(const void* g, void* l) {
  __builtin_amdgcn_global_load_lds(
      (const __attribute__((address_space(1))) void*)g,
      (__attribute__((address_space(3))) void*)l, 16, 0, 0);
}

// ---------------------------------------------------------------------------
__global__ __launch_bounds__(256) void k_f32_to_bf16(
    const float* __restrict__ in, u16* __restrict__ out, int n4) {
  int i = blockIdx.x * 256 + threadIdx.x;
  if (i >= n4) return;
  float4 v = reinterpret_cast<const float4*>(in)[i];
  ushort4 o;
  o.x = f2bf(v.x); o.y = f2bf(v.y); o.z = f2bf(v.z); o.w = f2bf(v.w);
  reinterpret_cast<ushort4*>(out)[i] = o;
}

// ---------------------------------------------------------------------------
__global__ __launch_bounds__(256) void k_transpose_bf16(
    const float* __restrict__ wq, const float* __restrict__ wk,
    const float* __restrict__ wv, u16* __restrict__ out) {
  __shared__ float tile[32][33];
  const float* src = (blockIdx.z == 0) ? wq : (blockIdx.z == 1) ? wk : wv;
  u16* dst = out + (size_t)blockIdx.z * DDSQ;
  int tx = threadIdx.x, ty = threadIdx.y;
  int bx = blockIdx.x * 32, by = blockIdx.y * 32;
#pragma unroll
  for (int i = 0; i < 4; ++i)
    tile[ty + 8 * i][tx] = src[(size_t)(by + ty + 8 * i) * DDIM + bx + tx];
  __syncthreads();
#pragma unroll
  for (int i = 0; i < 4; ++i)
    dst[(size_t)(bx + ty + 8 * i) * DDIM + by + tx] = f2bf(tile[tx][ty + 8 * i]);
}

// ---------------------------------------------------------------------------
__global__ __launch_bounds__(256) void k_bias_fuse(
    const float* __restrict__ ws, const float* __restrict__ bq,
    const float* __restrict__ bk, const float* __restrict__ bv,
    const float* __restrict__ bs, float* __restrict__ bf) {
  int idx = blockIdx.y;
  int s = idx / 3, t = idx - s * 3;
  const float* bt = (t == 0) ? bq : (t == 1) ? bk : bv;
  int lane = threadIdx.x & 63, wid = threadIdx.x >> 6;
  int e = blockIdx.x * 4 + wid;
  const float* wr = ws + (size_t)s * DDSQ + (size_t)e * DDIM;
  float p = 0.f;
  for (int j = lane; j < DDIM; j += 64) p += wr[j] * bt[j];
#pragma unroll
  for (int off = 32; off > 0; off >>= 1) p += __shfl_xor(p, off);
  if (lane == 0) bf[idx * DDIM + e] = p + bs[s * DDIM + e];
}

// ---------------------------------------------------------------------------
// m97-structure GEMM (known good) — used for weight-fuse + final only.
// C = A @ B^T (+bias); grid (8*Z or Z*8+nb, M/128).
// ---------------------------------------------------------------------------
template <typename OutT>
__global__ __launch_bounds__(256) void k_gemm_bt(
    const u16* __restrict__ A, const u16* __restrict__ B, OutT* __restrict__ C,
    const float* __restrict__ bias, int M, int N, int K,
    size_t za, size_t zb, size_t zc, size_t zbias, int zmode) {
  __shared__ u16 lds_a[128 * 32];
  __shared__ u16 lds_b[128 * 32];

  int z = blockIdx.x >> 3;
  int n_blk = blockIdx.x & 7;
  int m_blk = blockIdx.y;
  if (zmode == 1) { A += (size_t)(z / 3) * za; B += (size_t)(z % 3) * zb; }
  else            { A += (size_t)z * za;       B += (size_t)z * zb; }
  C += (size_t)z * zc;
  const float* biasz = bias ? (bias + (size_t)z * zbias) : nullptr;

  int m0 = m_blk * 128, n0 = n_blk * 128;
  int tid = threadIdx.x;
  int lane = tid & 63, wid = tid >> 6;
  int wm = wid >> 1, wn = wid & 1;

  f32x4 acc[4][4] = {};

  auto stage = [&](int k0) {
#pragma unroll
    for (int i = 0; i < 2; ++i) {
      int c = wid * 2 + i;
      int row = c * 16 + (lane >> 2);
      int col = (lane & 3) * 8;
      gload_lds16(A + (size_t)(m0 + row) * K + k0 + col, &lds_a[c * 512]);
      gload_lds16(B + (size_t)(n0 + row) * K + k0 + col, &lds_b[c * 512]);
    }
  };

  stage(0);
  int ar = (wm * 64 + (lane & 15)) * 32 + (lane >> 4) * 8;
  int br = (wn * 64 + (lane & 15)) * 32 + (lane >> 4) * 8;
  for (int k0 = 0;;) {
    __syncthreads();
    s16x8 af[4], bfr[4];
#pragma unroll
    for (int mi = 0; mi < 4; ++mi)
      af[mi] = *reinterpret_cast<const s16x8*>(&lds_a[ar + mi * 16 * 32]);
#pragma unroll
    for (int ni = 0; ni < 4; ++ni)
      bfr[ni] = *reinterpret_cast<const s16x8*>(&lds_b[br + ni * 16 * 32]);
#pragma unroll
    for (int mi = 0; mi < 4; ++mi)
#pragma unroll
      for (int ni = 0; ni < 4; ++ni)
        acc[mi][ni] = __builtin_amdgcn_mfma_f32_16x16x32_bf16(
            af[mi], bfr[ni], acc[mi][ni], 0, 0, 0);
    k0 += 32;
    if (k0 >= K) break;
    __syncthreads();
    stage(k0);
  }

#pragma unroll
  for (int mi = 0; mi < 4; ++mi) {
#pragma unroll
    for (int ni = 0; ni < 4; ++ni) {
      int colg = n0 + wn * 64 + ni * 16 + (lane & 15);
      float badd = biasz ? biasz[colg] : 0.f;
#pragma unroll
      for (int r = 0; r < 4; ++r) {
        int rowg = m0 + wm * 64 + mi * 16 + ((lane >> 4) << 2) + r;
        float v = acc[mi][ni][r] + badd;
        if constexpr (sizeof(OutT) == 2) C[(size_t)rowg * N + colg] = f2bf(v);
        else                             C[(size_t)rowg * N + colg] = v;
      }
    }
  }
}

// ---------------------------------------------------------------------------
// 256x256 pipelined GEMM (T3+T4+T5+T2):  C = A @ B^T + bias, bf16 out.
// BK=32, 512 threads = 8 waves (2m x 4n), per-wave 128x64 output.
// 3-ring LDS buffers (96 KB); prefetch distance 2 K-tiles; counted
// s_waitcnt vmcnt(4) once per tile (never 0 in loop); raw s_barrier;
// 2 phases/tile x 16 MFMA; setprio around MFMA.
// LDS swizzle: byte[5:4] ^= (row>>1)&3 — applied on ds_read addr AND
// (inverse, same XOR) on the per-lane global source addr; DMA dest linear.
// Per-wave load ledger: 4 loads/tile (2 A + 2 B), outstanding <= 8.
// grid: (Z*nbx + nb, M/256); A += z*za etc.
// ---------------------------------------------------------------------------
__global__ __launch_bounds__(512, 2) void k_gemm256(
    const u16* __restrict__ A, const u16* __restrict__ B, u16* __restrict__ C,
    const float* __restrict__ bias, int M, int N, int K,
    size_t za, size_t zb, size_t zc, size_t zbias, int nbx) {
  __shared__ u16 lds[3][2][8192];   // [ring][A/B][256*32]

  int z = blockIdx.x / nbx;
  int nb = blockIdx.x - z * nbx;
  const u16* Ag = A + (size_t)z * za;
  const u16* Bg = B + (size_t)z * zb;
  u16* Cg = C + (size_t)z * zc;
  const float* biasz = bias + (size_t)z * zbias;

  int m0 = blockIdx.y * 256, n0 = nb * 256;
  int tid = threadIdx.x;
  int lane = tid & 63, wid = tid >> 6;
  int wm = wid >> 2, wn = wid & 3;          // 2 x 4 waves, 128x64 each
  int NT = K >> 5;                          // K-tiles of 32

  // ---- staging precompute (per-lane global srcs, inverse-swizzled) ----
  int scb = ((lane & 3) * 16) ^ (((lane >> 3) & 3) << 4);
  const char* srcA[2]; const char* srcB[2]; int ldsc[2];
#pragma unroll
  for (int r = 0; r < 2; ++r) {
    int c = r * 8 + wid;
    int row = c * 16 + (lane >> 2);
    srcA[r] = (const char*)Ag + ((size_t)(m0 + row) * K) * 2 + scb;
    srcB[r] = (const char*)Bg + ((size_t)(n0 + row) * K) * 2 + scb;
    ldsc[r] = c * 1024;
  }
  char* lbase = (char*)&lds[0][0][0];

  // ---- fragment read offsets (swizzled) ----
  int fxor = ((lane >> 4) * 16) ^ (((lane >> 1) & 3) << 4);
  int aoff = (wm * 128 + (lane & 15)) * 64 + fxor;
  int boff = (wn * 64 + (lane & 15)) * 64 + fxor;

  f32x4 acc[8][4] = {};

#define STAGE_A(kt, rg)                                                   \
  {                                                                       \
    _Pragma("unroll") for (int r = 0; r < 2; ++r)                         \
        gload_lds16(srcA[r] + (size_t)(kt) * 64,                          \
                    lbase + (rg) * 32768 + ldsc[r]);                      \
  }
#define STAGE_B(kt, rg)                                                   \
  {                                                                       \
    _Pragma("unroll") for (int r = 0; r < 2; ++r)                         \
        gload_lds16(srcB[r] + (size_t)(kt) * 64,                          \
                    lbase + (rg) * 32768 + 16384 + ldsc[r]);              \
  }

  // prologue: tiles 0 -> ring0, 1 -> ring1   (8 loads/wave)
  STAGE_A(0, 0); STAGE_B(0, 0);
  STAGE_A(1, 1); STAGE_B(1, 1);
  __builtin_amdgcn_sched_barrier(0);
  asm volatile("s_waitcnt vmcnt(4)" ::: "memory");   // tile 0 landed
  __builtin_amdgcn_sched_barrier(0);
  __builtin_amdgcn_s_barrier();

  int ring = 0;
  for (int t = 0; t < NT; ++t) {
    int t2 = (t + 2 < NT) ? t + 2 : NT - 1;   // tail: dummy (keeps ledger)
    int rg2 = ring + 2; if (rg2 >= 3) rg2 -= 3;
    const char* bA = lbase + ring * 32768;
    const char* bB = bA + 16384;

    // ================= phase A =================
    s16x8 fb[4], fa[4];
#pragma unroll
    for (int ni = 0; ni < 4; ++ni)
      fb[ni] = *(const s16x8*)(bB + boff + ni * 1024);
#pragma unroll
    for (int mi = 0; mi < 4; ++mi)
      fa[mi] = *(const s16x8*)(bA + aoff + mi * 1024);
    STAGE_A(t2, rg2);
    __builtin_amdgcn_sched_barrier(0);
    __builtin_amdgcn_s_barrier();
    asm volatile("s_waitcnt lgkmcnt(0)" ::: "memory");
    __builtin_amdgcn_sched_barrier(0);
    __builtin_amdgcn_s_setprio(1);
#pragma unroll
    for (int mi = 0; mi < 4; ++mi)
#pragma unroll
      for (int ni = 0; ni < 4; ++ni)
        acc[mi][ni] = __builtin_amdgcn_mfma_f32_16x16x32_bf16(
            fa[mi], fb[ni], acc[mi][ni], 0, 0, 0);
    __builtin_amdgcn_s_setprio(0);
    __builtin_amdgcn_sched_barrier(0);
    __builtin_amdgcn_s_barrier();

    // ================= phase B =================
    s16x8 fa2[4];
#pragma unroll
    for (int mi = 0; mi < 4; ++mi)
      fa2[mi] = *(const s16x8*)(bA + aoff + 4096 + mi * 1024);
    STAGE_B(t2, rg2);
    __builtin_amdgcn_sched_barrier(0);
    asm volatile("s_waitcnt vmcnt(4)" ::: "memory");  // tile t+1 landed
    __builtin_amdgcn_sched_barrier(0);
    __builtin_amdgcn_s_barrier();
    asm volatile("s_waitcnt lgkmcnt(0)" ::: "memory");
    __builtin_amdgcn_sched_barrier(0);
    __builtin_amdgcn_s_setprio(1);
#pragma unroll
    for (int mi = 0; mi < 4; ++mi)
#pragma unroll
      for (int ni = 0; ni < 4; ++ni)
        acc[mi + 4][ni] = __builtin_amdgcn_mfma_f32_16x16x32_bf16(
            fa2[mi], fb[ni], acc[mi + 4][ni], 0, 0, 0);
    __builtin_amdgcn_s_setprio(0);
    __builtin_amdgcn_sched_barrier(0);
    __builtin_amdgcn_s_barrier();

    ring = ring + 1; if (ring == 3) ring = 0;
  }
#undef STAGE_A
#undef STAGE_B

  // ---- epilogue: C[row, col] += bias ----
#pragma unroll
  for (int mi = 0; mi < 8; ++mi) {
#pragma unroll
    for (int ni = 0; ni < 4; ++ni) {
      int colg = n0 + wn * 64 + ni * 16 + (lane & 15);
      float badd = biasz[colg];
#pragma unroll
      for (int r = 0; r < 4; ++r) {
        int rowg = m0 + wm * 128 + mi * 16 + ((lane >> 4) << 2) + r;
        Cg[(size_t)rowg * N + colg] = f2bf(acc[mi][ni][r] + badd);
      }
    }
  }
}

// ---------------------------------------------------------------------------
// per-position head-mix attention, ALL 4 scales fused. (unchanged)
// ---------------------------------------------------------------------------
__global__ __launch_bounds__(256) void k_attn_all(
    const u16* __restrict__ proj, u16* __restrict__ outbf,
    const float* __restrict__ sl, int rows) {
  __shared__ u16 kv[4][2][1024];
  int lane = threadIdx.x & 63, wid = threadIdx.x >> 6;
  int row = blockIdx.x * 4 + wid;
  int h = lane >> 2, dq = lane & 3;
  int doff = h * 64 + dq * 16;

  float l0 = sl[0], l1 = sl[1], l2 = sl[2], l3 = sl[3];
  float lm = fmaxf(fmaxf(l0, l1), fmaxf(l2, l3));
  float e0 = __expf(l0 - lm), e1 = __expf(l1 - lm), e2 = __expf(l2 - lm),
        e3 = __expf(l3 - lm);
  float esum = e0 + e1 + e2 + e3;
  float wsc4[4] = {e0 / esum, e1 / esum, e2 / esum, e3 / esum};

  float acc[16];
#pragma unroll
  for (int i = 0; i < 16; ++i) acc[i] = 0.f;

  for (int s = 0; s < 4; ++s) {
    const u16* kr = proj + ((size_t)(3 * s + 1) * rows + row) * DDIM;
    const u16* vr = proj + ((size_t)(3 * s + 2) * rows + row) * DDIM;
    asm volatile("s_waitcnt vmcnt(0) lgkmcnt(0)" ::: "memory");
    gload_lds16(kr + lane * 8,       &kv[wid][0][0]);
    gload_lds16(kr + 512 + lane * 8, &kv[wid][0][512]);
    gload_lds16(vr + lane * 8,       &kv[wid][1][0]);
    gload_lds16(vr + 512 + lane * 8, &kv[wid][1][512]);

    const u16* qr = proj + ((size_t)(3 * s) * rows + row) * DDIM + doff;
    u16x8 q0 = *reinterpret_cast<const u16x8*>(qr);
    u16x8 q1 = *reinterpret_cast<const u16x8*>(qr + 8);
    float qf[16];
#pragma unroll
    for (int i = 0; i < 8; ++i) {
      qf[i]     = b2f(q0[i]) * 0.125f;
      qf[8 + i] = b2f(q1[i]) * 0.125f;
    }
    asm volatile("s_waitcnt vmcnt(0)" ::: "memory");

    float sc[16];
#pragma unroll
    for (int g = 0; g < 16; ++g) {
      const u16* kp = &kv[wid][0][g * 64 + dq * 16];
      u16x8 k0 = *reinterpret_cast<const u16x8*>(kp);
      u16x8 k1 = *reinterpret_cast<const u16x8*>(kp + 8);
      float d = 0.f;
#pragma unroll
      for (int i = 0; i < 8; ++i) d = fmaf(qf[i], b2f(k0[i]), d);
#pragma unroll
      for (int i = 0; i < 8; ++i) d = fmaf(qf[8 + i], b2f(k1[i]), d);
      d += __shfl_xor(d, 1);
      d += __shfl_xor(d, 2);
      sc[g] = d;
    }

    float mx = sc[0];
#pragma unroll
    for (int g = 1; g < 16; ++g) mx = fmaxf(mx, sc[g]);
    float sum = 0.f;
#pragma unroll
    for (int g = 0; g < 16; ++g) { sc[g] = __expf(sc[g] - mx); sum += sc[g]; }
    float inv = wsc4[s] / sum;
#pragma unroll
    for (int g = 0; g < 16; ++g) sc[g] *= inv;

#pragma unroll
    for (int g = 0; g < 16; ++g) {
      float a = sc[g];
      const u16* vp = &kv[wid][1][g * 64 + dq * 16];
      u16x8 v0 = *reinterpret_cast<const u16x8*>(vp);
      u16x8 v1 = *reinterpret_cast<const u16x8*>(vp + 8);
#pragma unroll
      for (int i = 0; i < 8; ++i) {
        acc[i]     = fmaf(a, b2f(v0[i]), acc[i]);
        acc[8 + i] = fmaf(a, b2f(v1[i]), acc[8 + i]);
      }
    }
  }

  u16* op = outbf + (size_t)row * DDIM + doff;
  u16x8 o0, o1;
#pragma unroll
  for (int i = 0; i < 8; ++i) {
    o0[i] = f2bf(acc[i]);
    o1[i] = f2bf(acc[8 + i]);
  }
  *reinterpret_cast<u16x8*>(op) = o0;
  *reinterpret_cast<u16x8*>(op + 8) = o1;
}

// ---------------------------------------------------------------------------
extern "C" void kernel_launch(void* const* d_in, const int* in_sizes, int n_in,
                              void* d_out, int out_size, void* d_ws,
                              size_t ws_size, hipStream_t stream) {
  const float* x  = (const float*)d_in[0];
  const float* sl = (const float*)d_in[1];
  const float* wq = (const float*)d_in[2];
  const float* bq = (const float*)d_in[3];
  const float* wk = (const float*)d_in[4];
  const float* bk = (const float*)d_in[5];
  const float* wv = (const float*)d_in[6];
  const float* bv = (const float*)d_in[7];
  const float* wo = (const float*)d_in[8];
  const float* bo = (const float*)d_in[9];
  const float* ws = (const float*)d_in[10];
  const float* bs = (const float*)d_in[11];
  float* out = (float*)d_out;

  char* wsb = (char*)d_ws;
  size_t off = 0;
  u16* xbf    = (u16*)(wsb + off); off += (size_t)MM * DDIM * 2;   // 32 MB
  u16* wfus   = (u16*)(wsb + off); off += 12ull * DDSQ * 2;        // 24 MB
  u16* wobf   = (u16*)(wsb + off); off += DDSQ * 2;                // 2 MB
  float* bfus = (float*)(wsb + off); off += 65536;                 // 48 KB + pad
  u16* combc  = (u16*)(wsb + off); off += (size_t)MM * DDIM * 2;   // 32 MB
  char* dynr  = wsb + off;
  size_t fixed = off;

  int chunk = 4096;
  while (chunk > 1024 && fixed + (size_t)12 * chunk * DDIM * 2 > ws_size)
    chunk >>= 1;
  u16* projc = (u16*)dynr;
  u16* wtT  = (u16*)dynr;                      // prefuse overlay, 6 MB
  u16* wsbf = (u16*)(dynr + 3ull * DDSQ * 2);  // prefuse overlay, 8 MB

  int n4;
  n4 = MM * DDIM / 4;
  k_f32_to_bf16<<<(n4 + 255) / 256, 256, 0, stream>>>(x, xbf, n4);
  n4 = (int)(4 * DDSQ / 4);
  k_f32_to_bf16<<<(n4 + 255) / 256, 256, 0, stream>>>(ws, wsbf, n4);
  n4 = (int)(DDSQ / 4);
  k_f32_to_bf16<<<(n4 + 255) / 256, 256, 0, stream>>>(wo, wobf, n4);

  k_transpose_bf16<<<dim3(32, 32, 3), dim3(32, 8), 0, stream>>>(wq, wk, wv, wtT);
  k_bias_fuse<<<dim3(256, 12), 256, 0, stream>>>(ws, bq, bk, bv, bs, bfus);

  // fused weights (m97 kernel, known good)
  k_gemm_bt<u16><<<dim3(96, 8), 256, 0, stream>>>(
      wsbf, wtT, wfus, nullptr, 1024, 1024, 1024, DDSQ, DDSQ, DDSQ, 0, 1);

  // chunked: proj (12 batched, pipelined 256^2 GEMM) -> fused attention
  int nchunks = MM / chunk;
  for (int c = 0; c < nchunks; ++c) {
    const u16* xa = xbf + (size_t)c * chunk * DDIM;
    k_gemm256<<<dim3(48, chunk / 256), 512, 0, stream>>>(
        xa, wfus, projc, bfus, chunk, 1024, 1024,
        0, DDSQ, (size_t)chunk * DDIM, DDIM, 4);
    k_attn_all<<<dim3(chunk / 4), 256, 0, stream>>>(
        projc, combc + (size_t)c * chunk * DDIM, sl, chunk);
  }

  // single final GEMM: out = comb_bf @ wo^T + bo   (fp32 output)
  k_gemm_bt<float><<<dim3(8, 128), 256, 0, stream>>>(
      combc, wobf, out, bo, MM, 1024, 1024, 0, 0, 0, 0, 0);
}

// Round 5
// 723.386 us; speedup vs baseline: 1.2610x; 1.0429x over previous
//
#include <hip/hip_runtime.h>

// ---------------------------------------------------------------------------
// FractalAttention: B=4, L=4096, D=1024, H=16, DH=64, S=4
//
//  sq_s = x @ (ws[s]@wq).T + (ws[s]@bq + bs[s])   (same for k,v)
//  1. convert x, ws, wo to bf16; transpose wq/wk/wv to bf16
//  2. fuse weights:  Wf[s*3+t] = ws[s] @ w_t   (12x 1024^3, m97 GEMM)
//  3. fuse biases:   bf[s*3+t] = ws[s] @ b_t + bs[s]
//  4. per row-chunk: proj (12 batched) via 256x256 ring-4 counted-vmcnt
//     single-barrier-per-tile GEMM -> all-scale fused attention
//  5. single final GEMM: out = comb @ wo.T + bo   (pipelined, f32 out)
// ---------------------------------------------------------------------------

typedef unsigned short u16;
typedef __attribute__((ext_vector_type(8))) short s16x8;
typedef __attribute__((ext_vector_type(8))) unsigned short u16x8;
typedef __attribute__((ext_vector_type(4))) float f32x4;

#define MM 16384        // B*L
#define DDIM 1024
#define DDSQ 1048576ull // D*D

__device__ __forceinline__ u16 f2bf(float f) {
  unsigned u = __float_as_uint(f);
  u = (u + 0x7FFFu + ((u >> 16) & 1u)) >> 16;   // RNE
  return (u16)u;
}
__device__ __forceinline__ float b2f(u16 b) {
  return __uint_as_float(((unsigned)b) << 16);
}
__device__ __forceinline__ void gload_lds16(const void* g, void* l) {
  __builtin_amdgcn_global_load_lds(
      (const __attribute__((address_space(1))) void*)g,
      (__attribute__((address_space(3))) void*)l, 16, 0, 0);
}

// ---------------------------------------------------------------------------
__global__ __launch_bounds__(256) void k_f32_to_bf16(
    const float* __restrict__ in, u16* __restrict__ out, int n4) {
  int i = blockIdx.x * 256 + threadIdx.x;
  if (i >= n4) return;
  float4 v = reinterpret_cast<const float4*>(in)[i];
  ushort4 o;
  o.x = f2bf(v.x); o.y = f2bf(v.y); o.z = f2bf(v.z); o.w = f2bf(v.w);
  reinterpret_cast<ushort4*>(out)[i] = o;
}

// ---------------------------------------------------------------------------
__global__ __launch_bounds__(256) void k_transpose_bf16(
    const float* __restrict__ wq, const float* __restrict__ wk,
    const float* __restrict__ wv, u16* __restrict__ out) {
  __shared__ float tile[32][33];
  const float* src = (blockIdx.z == 0) ? wq : (blockIdx.z == 1) ? wk : wv;
  u16* dst = out + (size_t)blockIdx.z * DDSQ;
  int tx = threadIdx.x, ty = threadIdx.y;
  int bx = blockIdx.x * 32, by = blockIdx.y * 32;
#pragma unroll
  for (int i = 0; i < 4; ++i)
    tile[ty + 8 * i][tx] = src[(size_t)(by + ty + 8 * i) * DDIM + bx + tx];
  __syncthreads();
#pragma unroll
  for (int i = 0; i < 4; ++i)
    dst[(size_t)(bx + ty + 8 * i) * DDIM + by + tx] = f2bf(tile[tx][ty + 8 * i]);
}

// ---------------------------------------------------------------------------
__global__ __launch_bounds__(256) void k_bias_fuse(
    const float* __restrict__ ws, const float* __restrict__ bq,
    const float* __restrict__ bk, const float* __restrict__ bv,
    const float* __restrict__ bs, float* __restrict__ bf) {
  int idx = blockIdx.y;
  int s = idx / 3, t = idx - s * 3;
  const float* bt = (t == 0) ? bq : (t == 1) ? bk : bv;
  int lane = threadIdx.x & 63, wid = threadIdx.x >> 6;
  int e = blockIdx.x * 4 + wid;
  const float* wr = ws + (size_t)s * DDSQ + (size_t)e * DDIM;
  float p = 0.f;
  for (int j = lane; j < DDIM; j += 64) p += wr[j] * bt[j];
#pragma unroll
  for (int off = 32; off > 0; off >>= 1) p += __shfl_xor(p, off);
  if (lane == 0) bf[idx * DDIM + e] = p + bs[s * DDIM + e];
}

// ---------------------------------------------------------------------------
// m97-structure GEMM (known good) — used for weight-fuse only.
// ---------------------------------------------------------------------------
template <typename OutT>
__global__ __launch_bounds__(256) void k_gemm_bt(
    const u16* __restrict__ A, const u16* __restrict__ B, OutT* __restrict__ C,
    const float* __restrict__ bias, int M, int N, int K,
    size_t za, size_t zb, size_t zc, size_t zbias, int zmode) {
  __shared__ u16 lds_a[128 * 32];
  __shared__ u16 lds_b[128 * 32];

  int z = blockIdx.x >> 3;
  int n_blk = blockIdx.x & 7;
  int m_blk = blockIdx.y;
  if (zmode == 1) { A += (size_t)(z / 3) * za; B += (size_t)(z % 3) * zb; }
  else            { A += (size_t)z * za;       B += (size_t)z * zb; }
  C += (size_t)z * zc;
  const float* biasz = bias ? (bias + (size_t)z * zbias) : nullptr;

  int m0 = m_blk * 128, n0 = n_blk * 128;
  int tid = threadIdx.x;
  int lane = tid & 63, wid = tid >> 6;
  int wm = wid >> 1, wn = wid & 1;

  f32x4 acc[4][4] = {};

  auto stage = [&](int k0) {
#pragma unroll
    for (int i = 0; i < 2; ++i) {
      int c = wid * 2 + i;
      int row = c * 16 + (lane >> 2);
      int col = (lane & 3) * 8;
      gload_lds16(A + (size_t)(m0 + row) * K + k0 + col, &lds_a[c * 512]);
      gload_lds16(B + (size_t)(n0 + row) * K + k0 + col, &lds_b[c * 512]);
    }
  };

  stage(0);
  int ar = (wm * 64 + (lane & 15)) * 32 + (lane >> 4) * 8;
  int br = (wn * 64 + (lane & 15)) * 32 + (lane >> 4) * 8;
  for (int k0 = 0;;) {
    __syncthreads();
    s16x8 af[4], bfr[4];
#pragma unroll
    for (int mi = 0; mi < 4; ++mi)
      af[mi] = *reinterpret_cast<const s16x8*>(&lds_a[ar + mi * 16 * 32]);
#pragma unroll
    for (int ni = 0; ni < 4; ++ni)
      bfr[ni] = *reinterpret_cast<const s16x8*>(&lds_b[br + ni * 16 * 32]);
#pragma unroll
    for (int mi = 0; mi < 4; ++mi)
#pragma unroll
      for (int ni = 0; ni < 4; ++ni)
        acc[mi][ni] = __builtin_amdgcn_mfma_f32_16x16x32_bf16(
            af[mi], bfr[ni], acc[mi][ni], 0, 0, 0);
    k0 += 32;
    if (k0 >= K) break;
    __syncthreads();
    stage(k0);
  }

#pragma unroll
  for (int mi = 0; mi < 4; ++mi) {
#pragma unroll
    for (int ni = 0; ni < 4; ++ni) {
      int colg = n0 + wn * 64 + ni * 16 + (lane & 15);
      float badd = biasz ? biasz[colg] : 0.f;
#pragma unroll
      for (int r = 0; r < 4; ++r) {
        int rowg = m0 + wm * 64 + mi * 16 + ((lane >> 4) << 2) + r;
        float v = acc[mi][ni][r] + badd;
        if constexpr (sizeof(OutT) == 2) C[(size_t)rowg * N + colg] = f2bf(v);
        else                             C[(size_t)rowg * N + colg] = v;
      }
    }
  }
}

// ---------------------------------------------------------------------------
// 256x256 pipelined GEMM, ring-4 / distance-3 / 1 barrier per tile.
// C = A @ B^T + bias.  BK=32, 512 threads = 8 waves (2m x 4n), per-wave
// 128x64 output.  LDS: 4 rings x (16KB A + 16KB B) = 128 KB.
// Per tile: {12 ds_read_b128 + 4 stage gloads -> 32 MFMA (compiler-counted
// lgkm) -> vmcnt(8) (retires tile t+1, issued 2 tiles ago) -> s_barrier}.
// Ledger: 4 gloads/wave/tile, 12 outstanding steady state, never drained
// in-loop.  Ring t%4 is re-staged at tile t+1 (its readers finished at the
// end-of-tile-t barrier; DMA lands >=200cy after issue).
// XOR swizzle (verified round 4, conflicts = 0): slot ^= (row>>1)&3 on both
// the per-lane global source (write side) and the ds_read addr (read side).
// ---------------------------------------------------------------------------
template <typename OutT>
__global__ __launch_bounds__(512, 1) void k_gemm256(
    const u16* __restrict__ A, const u16* __restrict__ B, OutT* __restrict__ C,
    const float* __restrict__ bias, int M, int N, int K,
    size_t za, size_t zb, size_t zc, size_t zbias, int nbx) {
  __shared__ u16 lds[4][2][8192];   // [ring][A/B][256*32]

  int z = blockIdx.x / nbx;
  int nb = blockIdx.x - z * nbx;
  const u16* Ag = A + (size_t)z * za;
  const u16* Bg = B + (size_t)z * zb;
  OutT* Cg = C + (size_t)z * zc;
  const float* biasz = bias + (size_t)z * zbias;

  int m0 = blockIdx.y * 256, n0 = nb * 256;
  int tid = threadIdx.x;
  int lane = tid & 63, wid = tid >> 6;
  int wm = wid >> 2, wn = wid & 3;          // 2 x 4 waves, 128x64 each
  int NT = K >> 5;                          // K-tiles of 32

  // staging precompute (per-lane global srcs, inverse-swizzled)
  int scb = ((lane & 3) * 16) ^ (((lane >> 3) & 3) << 4);
  const char* srcA[2]; const char* srcB[2]; int ldsc[2];
#pragma unroll
  for (int r = 0; r < 2; ++r) {
    int c = r * 8 + wid;
    int row = c * 16 + (lane >> 2);
    srcA[r] = (const char*)Ag + ((size_t)(m0 + row) * K) * 2 + scb;
    srcB[r] = (const char*)Bg + ((size_t)(n0 + row) * K) * 2 + scb;
    ldsc[r] = c * 1024;
  }
  char* lbase = (char*)&lds[0][0][0];

  // fragment read offsets (swizzled)
  int fxor = ((lane >> 4) * 16) ^ (((lane >> 1) & 3) << 4);
  int aoff = (wm * 128 + (lane & 15)) * 64 + fxor;
  int boff = (wn * 64 + (lane & 15)) * 64 + fxor;

  f32x4 acc[8][4] = {};

#define STAGE_A(kt, rg)                                                   \
  {                                                                       \
    _Pragma("unroll") for (int r = 0; r < 2; ++r)                         \
        gload_lds16(srcA[r] + (size_t)(kt) * 64,                          \
                    lbase + (rg) * 32768 + ldsc[r]);                      \
  }
#define STAGE_B(kt, rg)                                                   \
  {                                                                       \
    _Pragma("unroll") for (int r = 0; r < 2; ++r)                         \
        gload_lds16(srcB[r] + (size_t)(kt) * 64,                          \
                    lbase + (rg) * 32768 + 16384 + ldsc[r]);              \
  }

  // prologue: tiles 0,1,2 -> rings 0,1,2   (12 loads/wave)
  STAGE_A(0, 0); STAGE_B(0, 0);
  STAGE_A(1, 1); STAGE_B(1, 1);
  STAGE_A(2, 2); STAGE_B(2, 2);
  asm volatile("s_waitcnt vmcnt(8)" ::: "memory");   // tile 0 landed
  asm volatile("s_barrier" ::: "memory");

  for (int t = 0; t < NT; ++t) {
    int rg = t & 3;
    int t3 = (t + 3 < NT) ? t + 3 : NT - 1;   // tail: dummy (keeps ledger)
    int rg3 = (rg + 3) & 3;                   // ring read in tile t-1
    const char* bA = lbase + rg * 32768;
    const char* bB = bA + 16384;

    s16x8 fb[4], fa[4], fa2[4];
#pragma unroll
    for (int ni = 0; ni < 4; ++ni)
      fb[ni] = *(const s16x8*)(bB + boff + ni * 1024);
#pragma unroll
    for (int mi = 0; mi < 4; ++mi)
      fa[mi] = *(const s16x8*)(bA + aoff + mi * 1024);
    STAGE_A(t3, rg3);
#pragma unroll
    for (int mi = 0; mi < 4; ++mi)
      fa2[mi] = *(const s16x8*)(bA + aoff + 4096 + mi * 1024);
    STAGE_B(t3, rg3);

    __builtin_amdgcn_s_setprio(1);
#pragma unroll
    for (int mi = 0; mi < 4; ++mi)
#pragma unroll
      for (int ni = 0; ni < 4; ++ni)
        acc[mi][ni] = __builtin_amdgcn_mfma_f32_16x16x32_bf16(
            fa[mi], fb[ni], acc[mi][ni], 0, 0, 0);
#pragma unroll
    for (int mi = 0; mi < 4; ++mi)
#pragma unroll
      for (int ni = 0; ni < 4; ++ni)
        acc[mi + 4][ni] = __builtin_amdgcn_mfma_f32_16x16x32_bf16(
            fa2[mi], fb[ni], acc[mi + 4][ni], 0, 0, 0);
    __builtin_amdgcn_s_setprio(0);

    asm volatile("s_waitcnt vmcnt(8)" ::: "memory");  // tile t+1 landed
    asm volatile("s_barrier" ::: "memory");           // fence + sync
  }
#undef STAGE_A
#undef STAGE_B

  // drain dummy tail DMAs before LDS can be reallocated to another block
  asm volatile("s_waitcnt vmcnt(0)" ::: "memory");

  // epilogue
#pragma unroll
  for (int mi = 0; mi < 8; ++mi) {
#pragma unroll
    for (int ni = 0; ni < 4; ++ni) {
      int colg = n0 + wn * 64 + ni * 16 + (lane & 15);
      float badd = biasz[colg];
#pragma unroll
      for (int r = 0; r < 4; ++r) {
        int rowg = m0 + wm * 128 + mi * 16 + ((lane >> 4) << 2) + r;
        float v = acc[mi][ni][r] + badd;
        if constexpr (sizeof(OutT) == 2) Cg[(size_t)rowg * N + colg] = f2bf(v);
        else                             Cg[(size_t)rowg * N + colg] = v;
      }
    }
  }
}

// ---------------------------------------------------------------------------
// per-position head-mix attention, ALL 4 scales fused. (unchanged)
// ---------------------------------------------------------------------------
__global__ __launch_bounds__(256) void k_attn_all(
    const u16* __restrict__ proj, u16* __restrict__ outbf,
    const float* __restrict__ sl, int rows) {
  __shared__ u16 kv[4][2][1024];
  int lane = threadIdx.x & 63, wid = threadIdx.x >> 6;
  int row = blockIdx.x * 4 + wid;
  int h = lane >> 2, dq = lane & 3;
  int doff = h * 64 + dq * 16;

  float l0 = sl[0], l1 = sl[1], l2 = sl[2], l3 = sl[3];
  float lm = fmaxf(fmaxf(l0, l1), fmaxf(l2, l3));
  float e0 = __expf(l0 - lm), e1 = __expf(l1 - lm), e2 = __expf(l2 - lm),
        e3 = __expf(l3 - lm);
  float esum = e0 + e1 + e2 + e3;
  float wsc4[4] = {e0 / esum, e1 / esum, e2 / esum, e3 / esum};

  float acc[16];
#pragma unroll
  for (int i = 0; i < 16; ++i) acc[i] = 0.f;

  for (int s = 0; s < 4; ++s) {
    const u16* kr = proj + ((size_t)(3 * s + 1) * rows + row) * DDIM;
    const u16* vr = proj + ((size_t)(3 * s + 2) * rows + row) * DDIM;
    asm volatile("s_waitcnt vmcnt(0) lgkmcnt(0)" ::: "memory");
    gload_lds16(kr + lane * 8,       &kv[wid][0][0]);
    gload_lds16(kr + 512 + lane * 8, &kv[wid][0][512]);
    gload_lds16(vr + lane * 8,       &kv[wid][1][0]);
    gload_lds16(vr + 512 + lane * 8, &kv[wid][1][512]);

    const u16* qr = proj + ((size_t)(3 * s) * rows + row) * DDIM + doff;
    u16x8 q0 = *reinterpret_cast<const u16x8*>(qr);
    u16x8 q1 = *reinterpret_cast<const u16x8*>(qr + 8);
    float qf[16];
#pragma unroll
    for (int i = 0; i < 8; ++i) {
      qf[i]     = b2f(q0[i]) * 0.125f;
      qf[8 + i] = b2f(q1[i]) * 0.125f;
    }
    asm volatile("s_waitcnt vmcnt(0)" ::: "memory");

    float sc[16];
#pragma unroll
    for (int g = 0; g < 16; ++g) {
      const u16* kp = &kv[wid][0][g * 64 + dq * 16];
      u16x8 k0 = *reinterpret_cast<const u16x8*>(kp);
      u16x8 k1 = *reinterpret_cast<const u16x8*>(kp + 8);
      float d = 0.f;
#pragma unroll
      for (int i = 0; i < 8; ++i) d = fmaf(qf[i], b2f(k0[i]), d);
#pragma unroll
      for (int i = 0; i < 8; ++i) d = fmaf(qf[8 + i], b2f(k1[i]), d);
      d += __shfl_xor(d, 1);
      d += __shfl_xor(d, 2);
      sc[g] = d;
    }

    float mx = sc[0];
#pragma unroll
    for (int g = 1; g < 16; ++g) mx = fmaxf(mx, sc[g]);
    float sum = 0.f;
#pragma unroll
    for (int g = 0; g < 16; ++g) { sc[g] = __expf(sc[g] - mx); sum += sc[g]; }
    float inv = wsc4[s] / sum;
#pragma unroll
    for (int g = 0; g < 16; ++g) sc[g] *= inv;

#pragma unroll
    for (int g = 0; g < 16; ++g) {
      float a = sc[g];
      const u16* vp = &kv[wid][1][g * 64 + dq * 16];
      u16x8 v0 = *reinterpret_cast<const u16x8*>(vp);
      u16x8 v1 = *reinterpret_cast<const u16x8*>(vp + 8);
#pragma unroll
      for (int i = 0; i < 8; ++i) {
        acc[i]     = fmaf(a, b2f(v0[i]), acc[i]);
        acc[8 + i] = fmaf(a, b2f(v1[i]), acc[8 + i]);
      }
    }
  }

  u16* op = outbf + (size_t)row * DDIM + doff;
  u16x8 o0, o1;
#pragma unroll
  for (int i = 0; i < 8; ++i) {
    o0[i] = f2bf(acc[i]);
    o1[i] = f2bf(acc[8 + i]);
  }
  *reinterpret_cast<u16x8*>(op) = o0;
  *reinterpret_cast<u16x8*>(op + 8) = o1;
}

// ---------------------------------------------------------------------------
extern "C" void kernel_launch(void* const* d_in, const int* in_sizes, int n_in,
                              void* d_out, int out_size, void* d_ws,
                              size_t ws_size, hipStream_t stream) {
  const float* x  = (const float*)d_in[0];
  const float* sl = (const float*)d_in[1];
  const float* wq = (const float*)d_in[2];
  const float* bq = (const float*)d_in[3];
  const float* wk = (const float*)d_in[4];
  const float* bk = (const float*)d_in[5];
  const float* wv = (const float*)d_in[6];
  const float* bv = (const float*)d_in[7];
  const float* wo = (const float*)d_in[8];
  const float* bo = (const float*)d_in[9];
  const float* ws = (const float*)d_in[10];
  const float* bs = (const float*)d_in[11];
  float* out = (float*)d_out;

  char* wsb = (char*)d_ws;
  size_t off = 0;
  u16* xbf    = (u16*)(wsb + off); off += (size_t)MM * DDIM * 2;   // 32 MB
  u16* wfus   = (u16*)(wsb + off); off += 12ull * DDSQ * 2;        // 24 MB
  u16* wobf   = (u16*)(wsb + off); off += DDSQ * 2;                // 2 MB
  float* bfus = (float*)(wsb + off); off += 65536;                 // 48 KB + pad
  u16* combc  = (u16*)(wsb + off); off += (size_t)MM * DDIM * 2;   // 32 MB
  char* dynr  = wsb + off;
  size_t fixed = off;

  int chunk = 4096;
  while (chunk > 1024 && fixed + (size_t)12 * chunk * DDIM * 2 > ws_size)
    chunk >>= 1;
  u16* projc = (u16*)dynr;
  u16* wtT  = (u16*)dynr;                      // prefuse overlay, 6 MB
  u16* wsbf = (u16*)(dynr + 3ull * DDSQ * 2);  // prefuse overlay, 8 MB

  int n4;
  n4 = MM * DDIM / 4;
  k_f32_to_bf16<<<(n4 + 255) / 256, 256, 0, stream>>>(x, xbf, n4);
  n4 = (int)(4 * DDSQ / 4);
  k_f32_to_bf16<<<(n4 + 255) / 256, 256, 0, stream>>>(ws, wsbf, n4);
  n4 = (int)(DDSQ / 4);
  k_f32_to_bf16<<<(n4 + 255) / 256, 256, 0, stream>>>(wo, wobf, n4);

  k_transpose_bf16<<<dim3(32, 32, 3), dim3(32, 8), 0, stream>>>(wq, wk, wv, wtT);
  k_bias_fuse<<<dim3(256, 12), 256, 0, stream>>>(ws, bq, bk, bv, bs, bfus);

  // fused weights (m97 kernel, known good)
  k_gemm_bt<u16><<<dim3(96, 8), 256, 0, stream>>>(
      wsbf, wtT, wfus, nullptr, 1024, 1024, 1024, DDSQ, DDSQ, DDSQ, 0, 1);

  // chunked: proj (12 batched, pipelined 256^2 GEMM) -> fused attention
  int nchunks = MM / chunk;
  for (int c = 0; c < nchunks; ++c) {
    const u16* xa = xbf + (size_t)c * chunk * DDIM;
    k_gemm256<u16><<<dim3(48, chunk / 256), 512, 0, stream>>>(
        xa, wfus, projc, bfus, chunk, 1024, 1024,
        0, DDSQ, (size_t)chunk * DDIM, DDIM, 4);
    k_attn_all<<<dim3(chunk / 4), 256, 0, stream>>>(
        projc, combc + (size_t)c * chunk * DDIM, sl, chunk);
  }

  // single final GEMM (pipelined): out = comb_bf @ wo^T + bo  (fp32 out)
  k_gemm256<float><<<dim3(4, 64), 512, 0, stream>>>(
      combc, wobf, out, bo, MM, 1024, 1024, 0, 0, 0, 0, 4);
}